// Round 1
// 188.273 us; speedup vs baseline: 1.2799x; 1.2799x over previous
//
#include <hip/hip_runtime.h>
#include <hip/hip_fp16.h>
#include <math.h>

#define Nn 10000
#define Ee 320000
#define EE 330000        // E + N self loops
#define INF_ 256
#define NH 4
#define OUTC 128
#define F1 512
#define F2 512
#define SLOPE 0.2f
#define STRIDE 80        // ELL row capacity (max in-degree ~56; P(overflow)~1e-13)

#define SC_BLOCKS 1290       // ceil(EE/256)
#define CONVX_BLOCKS 2500    // Nn*INF_/(256*4)  (float4-vectorized)
#define TW1_BLOCKS 512       // (F1/64)*(INF_/4)
#define TW2_BLOCKS 1024      // (F2/64)*(F1/4)

static __device__ __forceinline__ float lrelu(float x) { return fmaxf(x, SLOPE * x); }

using frag_ab = __attribute__((ext_vector_type(8))) _Float16;
using frag_c  = __attribute__((ext_vector_type(4))) float;

// ---------------- prep: ELL scatter (self-counting, no scan) + fp16 conversions ----------------
__global__ void prep(const int* __restrict__ ei, int* counts, int* __restrict__ csr,
                     const float* __restrict__ x, const float* __restrict__ W1,
                     const float* __restrict__ W2, _Float16* __restrict__ xh,
                     _Float16* __restrict__ w1t, _Float16* __restrict__ w2t) {
    int b = blockIdx.x, t = threadIdx.x;
    if (b < SC_BLOCKS) {
        int e = b * 256 + t;
        if (e < EE) {
            int src, dst;
            if (e < Ee) { src = ei[e]; dst = ei[Ee + e]; }
            else        { src = e - Ee; dst = e - Ee; }
            int slot = atomicAdd(&counts[dst], 1);
            if (slot < STRIDE) csr[dst * STRIDE + slot] = src;
        }
    } else if (b < SC_BLOCKS + CONVX_BLOCKS) {
        int i = ((b - SC_BLOCKS) * 256 + t) * 4;
        float4 v = *(const float4*)(x + i);
        _Float16 oh[4];
        oh[0] = (_Float16)v.x; oh[1] = (_Float16)v.y;
        oh[2] = (_Float16)v.z; oh[3] = (_Float16)v.w;
        *(float2*)(xh + i) = *(float2*)oh;
    } else if (b < SC_BLOCKS + CONVX_BLOCKS + TW1_BLOCKS) {
        int bb = b - SC_BLOCKS - CONVX_BLOCKS;
        int n = (bb & 7) * 64 + (t & 63);
        int k = (bb >> 3) * 4 + (t >> 6);
        w1t[(size_t)n * INF_ + k] = (_Float16)W1[(size_t)k * F1 + n];
    } else {
        int bb = b - SC_BLOCKS - CONVX_BLOCKS - TW1_BLOCKS;
        int n = (bb & 7) * 64 + (t & 63);
        int k = (bb >> 3) * 4 + (t >> 6);
        w2t[(size_t)n * F1 + k] = (_Float16)W2[(size_t)k * F2 + n];
    }
}

// ---------------- MFMA fp16 GEMM + fused alpha dots (head-major alpha output) ----------------
#define LDK 40
__global__ __launch_bounds__(256) void mfma_gemm(const _Float16* __restrict__ A,
                                                 const _Float16* __restrict__ BT,
                                                 _Float16* __restrict__ C,
                                                 const float* __restrict__ a_src,
                                                 const float* __restrict__ a_dst,
                                                 float* __restrict__ as_out,
                                                 float* __restrict__ ad_out,
                                                 int M, int K) {
    __shared__ _Float16 As[64 * LDK];
    __shared__ _Float16 Bs[128 * LDK];
    const int tid = threadIdx.x;
    const int wave = tid >> 6, lane = tid & 63;
    const int q = lane >> 4, ml = lane & 15;
    const int bm = blockIdx.x * 64, bn = blockIdx.y * 128;
    const int head = blockIdx.y;
    const int srow = tid >> 2, scol = (tid & 3) * 8;

    frag_c acc[8];
#pragma unroll
    for (int f = 0; f < 8; f++)
#pragma unroll
        for (int r = 0; r < 4; r++) acc[f][r] = 0.f;

    for (int k0 = 0; k0 < K; k0 += 32) {
        int gm = bm + srow;
        frag_ab av;
        if (gm < M) av = *(const frag_ab*)(A + (size_t)gm * K + k0 + scol);
        else {
#pragma unroll
            for (int j = 0; j < 8; j++) av[j] = (_Float16)0.f;
        }
        *(frag_ab*)&As[srow * LDK + scol] = av;
        *(frag_ab*)&Bs[srow * LDK + scol] =
            *(const frag_ab*)(BT + (size_t)(bn + srow) * K + k0 + scol);
        *(frag_ab*)&Bs[(64 + srow) * LDK + scol] =
            *(const frag_ab*)(BT + (size_t)(bn + 64 + srow) * K + k0 + scol);
        __syncthreads();
        frag_ab a = *(frag_ab*)&As[(wave * 16 + ml) * LDK + q * 8];
#pragma unroll
        for (int f = 0; f < 8; f++) {
            frag_ab b = *(frag_ab*)&Bs[(f * 16 + ml) * LDK + q * 8];
            acc[f] = __builtin_amdgcn_mfma_f32_16x16x32_f16(a, b, acc[f], 0, 0, 0);
        }
        __syncthreads();
    }
    float asum[4] = {}, dsum[4] = {};
#pragma unroll
    for (int f = 0; f < 8; f++) {
        int cl = f * 16 + ml;
        int col = bn + cl;
        float sa = a_src[head * 128 + cl];
        float da = a_dst[head * 128 + cl];
#pragma unroll
        for (int r = 0; r < 4; r++) {
            int row = bm + wave * 16 + q * 4 + r;
            if (row < M) C[(size_t)row * (NH * 128) + col] = (_Float16)acc[f][r];
            asum[r] += acc[f][r] * sa;
            dsum[r] += acc[f][r] * da;
        }
    }
#pragma unroll
    for (int r = 0; r < 4; r++) {
#pragma unroll
        for (int off = 1; off < 16; off <<= 1) {
            asum[r] += __shfl_xor(asum[r], off);
            dsum[r] += __shfl_xor(dsum[r], off);
        }
    }
    if (ml == 0) {
#pragma unroll
        for (int r = 0; r < 4; r++) {
            int row = bm + wave * 16 + q * 4 + r;
            if (row < M) {
                as_out[(size_t)head * M + row] = asum[r];
                ad_out[(size_t)head * M + row] = dsum[r];
            }
        }
    }
}

// ---------------- fused softmax + aggregation, layer 1 ----------------
// Block = 16 nodes x 1 head (head = blockIdx&3 -> XCD slice, L2-resident).
// Quarter-wave = one node. Pass 1: single gather pass -> (src, logit) to LDS + max.
// Pass 2: LDS-local exp + sum (no global traffic). Then shuffle-free 8-edge-unroll
// aggregation from LDS. ew rows are wave-private -> no barriers needed.
__global__ __launch_bounds__(256) void passAB1(const int* __restrict__ counts,
                                               const int* __restrict__ csr,
                                               const float* __restrict__ as,
                                               const float* __restrict__ ad,
                                               const _Float16* __restrict__ hh,
                                               const float* __restrict__ b1,
                                               _Float16* __restrict__ agg) {
    __shared__ int2 ew[16][84];   // stride 84 -> 2-way max bank aliasing (free)
    int head = blockIdx.x & 3;
    int qw = threadIdx.x >> 4;
    int l = threadIdx.x & 15;
    int n = (blockIdx.x >> 2) * 16 + qw;
    int deg = counts[n]; if (deg > STRIDE) deg = STRIDE;
    int pdeg = (deg + 7) & ~7;
    const float* ash = as + (size_t)head * Nn;
    float adh = ad[(size_t)head * Nn + n];
    int base = n * STRIDE;
    float m = -1e30f;
    for (int k = l; k < pdeg; k += 16) {
        int src = 0; float v = -1e30f;
        if (k < deg) {
            src = csr[base + k];
            v = lrelu(ash[src] + adh);
        }
        ew[qw][k] = make_int2(src, __float_as_int(v));
        m = fmaxf(m, v);
    }
    m = fmaxf(m, __shfl_xor(m, 1));
    m = fmaxf(m, __shfl_xor(m, 2));
    m = fmaxf(m, __shfl_xor(m, 4));
    m = fmaxf(m, __shfl_xor(m, 8));
    float s = 0.f;
    for (int k = l; k < pdeg; k += 16) {
        float e = __expf(__int_as_float(ew[qw][k].y) - m);
        ew[qw][k].y = __float_as_int(e);
        s += e;
    }
    s += __shfl_xor(s, 1);
    s += __shfl_xor(s, 2);
    s += __shfl_xor(s, 4);
    s += __shfl_xor(s, 8);
    float inv = 1.f / (s + 1e-16f);
    int c = head * 128 + (l << 3);
    float acc[8] = {};
    for (int kk = 0; kk < pdeg; kk += 8) {
        int2 p[8];
#pragma unroll
        for (int j = 0; j < 8; j++) p[j] = ew[qw][kk + j];
#pragma unroll
        for (int j = 0; j < 8; j++) {
            float w = __int_as_float(p[j].y);
            frag_ab r = *(const frag_ab*)(hh + (size_t)p[j].x * F1 + c);
#pragma unroll
            for (int u = 0; u < 8; u++) acc[u] = fmaf((float)r[u], w, acc[u]);
        }
    }
    _Float16 oh[8];
#pragma unroll
    for (int j = 0; j < 8; j++)
        oh[j] = (_Float16)fmaxf(acc[j] * inv + b1[c + j], 0.f);
    *(float4*)&agg[(size_t)n * F1 + c] = *(float4*)oh;
}

// ---------------- fused softmax + aggregation, layer 2 -> fp16 tmp ----------------
__global__ __launch_bounds__(256) void passAB2(const int* __restrict__ counts,
                                               const int* __restrict__ csr,
                                               const float* __restrict__ as,
                                               const float* __restrict__ ad,
                                               const _Float16* __restrict__ hh,
                                               _Float16* __restrict__ tmp) {
    __shared__ int2 ew[16][84];
    int head = blockIdx.x & 3;
    int qw = threadIdx.x >> 4;
    int l = threadIdx.x & 15;
    int n = (blockIdx.x >> 2) * 16 + qw;
    int deg = counts[n]; if (deg > STRIDE) deg = STRIDE;
    int pdeg = (deg + 7) & ~7;
    const float* ash = as + (size_t)head * Nn;
    float adh = ad[(size_t)head * Nn + n];
    int base = n * STRIDE;
    float m = -1e30f;
    for (int k = l; k < pdeg; k += 16) {
        int src = 0; float v = -1e30f;
        if (k < deg) {
            src = csr[base + k];
            v = lrelu(ash[src] + adh);
        }
        ew[qw][k] = make_int2(src, __float_as_int(v));
        m = fmaxf(m, v);
    }
    m = fmaxf(m, __shfl_xor(m, 1));
    m = fmaxf(m, __shfl_xor(m, 2));
    m = fmaxf(m, __shfl_xor(m, 4));
    m = fmaxf(m, __shfl_xor(m, 8));
    float s = 0.f;
    for (int k = l; k < pdeg; k += 16) {
        float e = __expf(__int_as_float(ew[qw][k].y) - m);
        ew[qw][k].y = __float_as_int(e);
        s += e;
    }
    s += __shfl_xor(s, 1);
    s += __shfl_xor(s, 2);
    s += __shfl_xor(s, 4);
    s += __shfl_xor(s, 8);
    float inv = 1.f / (s + 1e-16f);
    int c = head * 128 + (l << 3);
    float acc[8] = {};
    for (int kk = 0; kk < pdeg; kk += 8) {
        int2 p[8];
#pragma unroll
        for (int j = 0; j < 8; j++) p[j] = ew[qw][kk + j];
#pragma unroll
        for (int j = 0; j < 8; j++) {
            float w = __int_as_float(p[j].y);
            frag_ab r = *(const frag_ab*)(hh + (size_t)p[j].x * F2 + c);
#pragma unroll
            for (int u = 0; u < 8; u++) acc[u] = fmaf((float)r[u], w, acc[u]);
        }
    }
    float qq = 0.25f * inv;
    _Float16 oh[8];
#pragma unroll
    for (int j = 0; j < 8; j++) oh[j] = (_Float16)(acc[j] * qq);
    *(float4*)&tmp[(size_t)n * F2 + c] = *(float4*)oh;   // [n][head*128+ch], fp16
}

// ---------------- reduce 4 heads + bias -> d_out (fp16 tmp [n][head][128]) ----------------
__global__ void reduce4(const _Float16* __restrict__ tmp, const float* __restrict__ b2,
                        float* __restrict__ out) {
    int i = blockIdx.x * 256 + threadIdx.x;
    if (i >= Nn * OUTC) return;
    int n = i >> 7, oc = i & 127;
    const _Float16* tp = tmp + (size_t)n * 512 + oc;
    out[i] = (float)tp[0] + (float)tp[128] + (float)tp[256] + (float)tp[384] + b2[oc];
}

extern "C" void kernel_launch(void* const* d_in, const int* in_sizes, int n_in,
                              void* d_out, int out_size, void* d_ws, size_t ws_size,
                              hipStream_t stream) {
    const float* x      = (const float*)d_in[0];
    const int*   ei     = (const int*)d_in[1];
    const float* W1     = (const float*)d_in[2];
    const float* a_src1 = (const float*)d_in[3];
    const float* a_dst1 = (const float*)d_in[4];
    const float* b1     = (const float*)d_in[5];
    const float* W2     = (const float*)d_in[6];
    const float* a_src2 = (const float*)d_in[7];
    const float* a_dst2 = (const float*)d_in[8];
    const float* b2     = (const float*)d_in[9];
    float* out = (float*)d_out;

    const size_t NF = (size_t)Nn * F1;
    float* f = (float*)d_ws;
    _Float16* tmp = (_Float16*)f;        // NF halves (region reserves NF floats)
    float* as1   = f + NF;
    float* ad1   = as1 + Nn;
    // head-major alpha arrays: [NH][Nn]
    float* as1h  = as1;                  // NH*Nn floats
    float* ad1h  = as1 + (size_t)NH * Nn;
    float* as2h  = ad1h + (size_t)NH * Nn;
    float* ad2h  = as2h + (size_t)NH * Nn;
    (void)ad1;
    int* csr     = (int*)(ad2h + (size_t)NH * Nn);   // Nn*STRIDE ints (ELL)
    _Float16* hh   = (_Float16*)(csr + (size_t)Nn * STRIDE);
    _Float16* aggh = hh + NF;
    _Float16* xh   = aggh + NF;
    _Float16* w1t  = xh + (size_t)Nn * INF_;
    _Float16* w2t  = w1t + (size_t)F1 * INF_;
    int* counts    = (int*)(w2t + (size_t)F2 * F1);  // Nn ints

    // zero degree counters, then one fused prep launch: ELL scatter (self-counting,
    // no count/scan chain) + x->fp16 + W1/W2 transposes
    (void)hipMemsetAsync(counts, 0, Nn * sizeof(int), stream);
    prep<<<SC_BLOCKS + CONVX_BLOCKS + TW1_BLOCKS + TW2_BLOCKS, 256, 0, stream>>>(
        ei, counts, csr, x, W1, W2, xh, w1t, w2t);

    // Layer 1
    mfma_gemm<<<dim3((Nn + 63) / 64, F1 / 128), 256, 0, stream>>>(
        xh, w1t, hh, a_src1, a_dst1, as1h, ad1h, Nn, INF_);
    passAB1<<<(Nn / 16) * 4, 256, 0, stream>>>(counts, csr, as1h, ad1h, hh, b1, aggh);

    // Layer 2
    mfma_gemm<<<dim3((Nn + 63) / 64, F2 / 128), 256, 0, stream>>>(
        aggh, w2t, hh, a_src2, a_dst2, as2h, ad2h, Nn, F1);
    passAB2<<<(Nn / 16) * 4, 256, 0, stream>>>(counts, csr, as2h, ad2h, hh, tmp);
    reduce4<<<(Nn * OUTC + 255) / 256, 256, 0, stream>>>(tmp, b2, out);
}